// Round 7
// baseline (396.009 us; speedup 1.0000x reference)
//
#include <hip/hip_runtime.h>

#define N_NODES 50000
#define D_IN 256
#define D_OUT 128
#define N_POS 1600000
#define N_PRED 500000

#define G_BUCKETS 782        // ceil(50000/64) buckets of 64 nodes
#define GPAD 1024
#define SB 160               // scatter blocks
#define CHUNK 10000          // SB*CHUNK == N_POS exactly
#define CAP 4096             // max edges/bucket (mean 2048, sigma ~45)

typedef __attribute__((ext_vector_type(8))) short short8;
typedef __attribute__((ext_vector_type(4))) float f32x4;

// ---- bf16 helpers (RNE) ----
__device__ __forceinline__ unsigned short f2bf(float f) {
    unsigned int u = __float_as_uint(f);
    u += 0x7FFFu + ((u >> 16) & 1u);
    return (unsigned short)(u >> 16);
}
__device__ __forceinline__ unsigned int pk2(float a, float b) {   // bf16(a) | bf16(b)<<16
    unsigned int ua = __float_as_uint(a), ub = __float_as_uint(b);
    ua += 0x7FFFu + ((ua >> 16) & 1u);
    ub += 0x7FFFu + ((ub >> 16) & 1u);
    return (ua >> 16) | (ub & 0xFFFF0000u);
}
__device__ __forceinline__ float bflo(unsigned int u) { return __uint_as_float(u << 16); }
__device__ __forceinline__ float bfhi(unsigned int u) { return __uint_as_float(u & 0xFFFF0000u); }

// ------- Wf = W1@Wc packed into MFMA B-fragment layout; bf = b1@Wc -------
__global__ void fuse_weights_k(const float* __restrict__ W1, const float* __restrict__ Wc,
                               const float* __restrict__ b1,
                               unsigned short* __restrict__ Bp, float* __restrict__ bf) {
    int gid = blockIdx.x * blockDim.x + threadIdx.x;   // 0..32767
    int k = gid >> 7;          // K dim
    int n = gid & 127;         // N dim
    float acc = 0.f;
    #pragma unroll 4
    for (int kk = 0; kk < D_IN; ++kk)
        acc += W1[k * D_IN + kk] * Wc[kk * D_OUT + n];
    int ks = k >> 5, q = (k >> 3) & 3, jj = k & 7;
    int nt = n >> 4, nl = n & 15;
    int lane = q * 16 + nl;
    Bp[(((long)(ks * 8 + nt)) * 64 + lane) * 8 + jj] = f2bf(acc);
    if (gid < D_OUT) {
        float accb = 0.f;
        for (int kk = 0; kk < D_IN; ++kk)
            accb += b1[kk] * Wc[kk * D_OUT + gid];
        bf[gid] = accb;
    }
}

__global__ void zero_int_k(int* __restrict__ p, int n) {
    int i = blockIdx.x * blockDim.x + threadIdx.x;
    if (i < n) p[i] = 0;
}

// ---------------- bucket partition ----------------
__global__ __launch_bounds__(256) void bucket_count_k(const int* __restrict__ col,
                                                      int* __restrict__ bcnt) {
    __shared__ int hist[GPAD];
    int t = threadIdx.x;
    for (int i = t; i < GPAD; i += 256) hist[i] = 0;
    __syncthreads();
    int e0 = blockIdx.x * CHUNK;
    for (int i = t; i < CHUNK; i += 256)
        atomicAdd(&hist[col[e0 + i] >> 6], 1);
    __syncthreads();
    for (int g = t; g < G_BUCKETS; g += 256) {
        int c = hist[g];
        if (c) atomicAdd(&bcnt[g], c);
    }
}

__global__ __launch_bounds__(1024) void scan_bucket_k(const int* __restrict__ bcnt,
                                                      int* __restrict__ boffs,
                                                      int* __restrict__ bfill,
                                                      int* __restrict__ offs) {
    __shared__ int s[1024];
    int t = threadIdx.x;
    int v = (t < G_BUCKETS) ? bcnt[t] : 0;
    s[t] = v;
    __syncthreads();
    for (int d = 1; d < 1024; d <<= 1) {
        int add = (t >= d) ? s[t - d] : 0;
        __syncthreads();
        s[t] += add;
        __syncthreads();
    }
    int ex = s[t] - v;
    if (t < G_BUCKETS) { boffs[t] = ex; bfill[t] = ex; }
    if (t == G_BUCKETS - 1) boffs[G_BUCKETS] = ex + v;
    if (t == 0) offs[N_NODES] = N_POS;
}

// bin chunk edges by bucket in LDS, write out bucket-contiguous bursts
__global__ __launch_bounds__(256) void bucket_scatter_k(const int* __restrict__ row,
                                                        const int* __restrict__ col,
                                                        int* __restrict__ bfill,
                                                        unsigned int* __restrict__ eb) {
    __shared__ int hist[GPAD];
    __shared__ int lofs[GPAD];
    __shared__ int fill2[GPAD];
    __shared__ int base[GPAD];
    __shared__ int part[256];
    __shared__ unsigned int stag[CHUNK];
    int t = threadIdx.x;
    for (int i = t; i < GPAD; i += 256) { hist[i] = 0; fill2[i] = 0; }
    __syncthreads();
    int e0 = blockIdx.x * CHUNK;
    for (int i = t; i < CHUNK; i += 256)
        atomicAdd(&hist[col[e0 + i] >> 6], 1);
    __syncthreads();
    int h[4], p4 = 0;
    #pragma unroll
    for (int i = 0; i < 4; ++i) { h[i] = hist[4 * t + i]; p4 += h[i]; }
    part[t] = p4;
    __syncthreads();
    for (int d = 1; d < 256; d <<= 1) {
        int add = (t >= d) ? part[t - d] : 0;
        __syncthreads();
        part[t] += add;
        __syncthreads();
    }
    int ex = part[t] - p4;
    #pragma unroll
    for (int i = 0; i < 4; ++i) { lofs[4 * t + i] = ex; ex += h[i]; }
    __syncthreads();
    for (int g = t; g < G_BUCKETS; g += 256) {
        int c = hist[g];
        base[g] = c ? atomicAdd(&bfill[g], c) : 0;
    }
    for (int i = t; i < CHUNK; i += 256) {
        int c = col[e0 + i];
        int g = c >> 6;
        unsigned int u = (unsigned int)row[e0 + i] | ((unsigned int)(c & 63) << 16)
                       | ((unsigned int)g << 22);
        int lp = atomicAdd(&fill2[g], 1);
        stag[lofs[g] + lp] = u;
    }
    __syncthreads();
    for (int i = t; i < CHUNK; i += 256) {
        unsigned int u = stag[i];
        int g = u >> 22;
        eb[base[g] + (i - lofs[g])] = u;
    }
}

// ---- per-bucket CSR build: node-sorted ushort rows, contiguous writes; offs + dinv ----
__global__ __launch_bounds__(256) void csr_build_k(const int* __restrict__ boffs,
                                                   const unsigned int* __restrict__ eb,
                                                   unsigned short* __restrict__ csr,
                                                   int* __restrict__ offs,
                                                   float* __restrict__ dinv) {
    __shared__ unsigned int stag[CAP];
    __shared__ unsigned short stag2[CAP];
    __shared__ int hist[64], lofs[64], fill[64];
    int t = threadIdx.x;
    int g = blockIdx.x;
    int s = boffs[g], e = boffs[g + 1];
    int cnt = e - s;
    if (t < 64) { hist[t] = 0; fill[t] = 0; }
    __syncthreads();
    for (int i = t; i < cnt; i += 256) {
        unsigned int u = eb[s + i];
        stag[i] = u;
        atomicAdd(&hist[(u >> 16) & 63], 1);
    }
    __syncthreads();
    if (t == 0) {
        int run = 0;
        for (int k = 0; k < 64; ++k) { lofs[k] = run; run += hist[k]; }
    }
    __syncthreads();
    if (t < 64) {
        int v = g * 64 + t;
        if (v < N_NODES) {
            offs[v] = s + lofs[t];
            dinv[v] = rsqrtf((float)hist[t] + 1.0f);   // +1 self loop
        }
    }
    for (int i = t; i < cnt; i += 256) {
        unsigned int u = stag[i];
        int nl = (u >> 16) & 63;
        int lp = atomicAdd(&fill[nl], 1);
        stag2[lofs[nl] + lp] = (unsigned short)(u & 0xFFFF);
    }
    __syncthreads();
    for (int i = t; i < cnt; i += 256)
        csr[s + i] = stag2[i];
}

// ------- MFMA GEMM: hs[slice][node][32cols] = bf16( dinv[v] * (x @ Wf + bf) ) -------
__global__ __launch_bounds__(256) void gemm_mfma_k(const float* __restrict__ x,
                                                   const uint4* __restrict__ Bp,
                                                   const float* __restrict__ bf,
                                                   const float* __restrict__ dinv,
                                                   unsigned short* __restrict__ hsb) {
    __shared__ unsigned short ot[4][16 * 128];   // 16 KB epilogue staging
    const int wave = threadIdx.x >> 6;
    const int lane = threadIdx.x & 63;
    const int q    = lane >> 4;
    const int ml   = lane & 15;
    const int m0   = blockIdx.x * 64 + wave * 16;

    f32x4 acc[8];
    #pragma unroll
    for (int t = 0; t < 8; ++t) acc[t] = (f32x4){0.f, 0.f, 0.f, 0.f};

    long arow = m0 + ml; if (arow > N_NODES - 1) arow = N_NODES - 1;
    const float* xrow = x + arow * D_IN + q * 8;

    #pragma unroll
    for (int ks = 0; ks < 8; ++ks) {
        float4 xa = *(const float4*)(xrow + ks * 32);
        float4 xb = *(const float4*)(xrow + ks * 32 + 4);
        union { short8 s; unsigned int u[4]; } af;
        af.u[0] = pk2(xa.x, xa.y);
        af.u[1] = pk2(xa.z, xa.w);
        af.u[2] = pk2(xb.x, xb.y);
        af.u[3] = pk2(xb.z, xb.w);
        #pragma unroll
        for (int nt = 0; nt < 8; ++nt) {
            union { uint4 v; short8 s; } bu;
            bu.v = Bp[(long)(ks * 8 + nt) * 64 + lane];
            acc[nt] = __builtin_amdgcn_mfma_f32_16x16x32_bf16(af.s, bu.s, acc[nt], 0, 0, 0);
        }
    }

    float dv[4];
    #pragma unroll
    for (int r = 0; r < 4; ++r) {
        int v = m0 + q * 4 + r;
        dv[r] = dinv[v > N_NODES - 1 ? N_NODES - 1 : v];
    }
    unsigned short* o = ot[wave];
    #pragma unroll
    for (int nt = 0; nt < 8; ++nt) {
        float bn = bf[nt * 16 + ml];
        #pragma unroll
        for (int r = 0; r < 4; ++r) {
            float val = dv[r] * (acc[nt][r] + bn);
            o[(q * 4 + r) * 128 + nt * 16 + ml] = f2bf(val);
        }
    }
    __syncthreads();
    // sliced store: slice s of rows r: 16 rows x 64 B, lane = r*4 + part
    {
        int r = lane >> 2, p = lane & 3;
        int v = m0 + r;
        if (v < N_NODES) {
            #pragma unroll
            for (int s = 0; s < 4; ++s) {
                uint4 val = *(const uint4*)((const char*)o + r * 256 + s * 64 + p * 16);
                *(uint4*)((char*)hsb + (long)(s * N_NODES + v) * 64 + p * 16) = val;
            }
        }
    }
}

// ---- sliced aggregation: slice table (3.2 MB) is L2-resident; 16 lanes/edge ----
// wave = 1 node; 4 edge-groups of 16 lanes; lane li owns cols 2li,2li+1 of the slice.
__global__ __launch_bounds__(256) void aggregate_slice_k(const int* __restrict__ offs,
                                                         const unsigned short* __restrict__ csr,
                                                         const unsigned int* __restrict__ hss,
                                                         const float* __restrict__ dinv,
                                                         const float* __restrict__ bc,
                                                         unsigned int* __restrict__ feats,
                                                         int s) {
    int v    = blockIdx.x * 4 + (threadIdx.x >> 6);
    int lane = threadIdx.x & 63;
    int grp  = lane >> 4, li = lane & 15;
    int s0 = offs[v], s1 = offs[v + 1];

    float a0 = 0.f, a1 = 0.f;
    int i = s0 + grp;
    for (; i + 4 < s1; i += 8) {          // 2 edges per group per iter (8 gathers/wave)
        int r0 = csr[i];
        int r1 = csr[i + 4];
        unsigned int u0 = hss[r0 * 16 + li];
        unsigned int u1 = hss[r1 * 16 + li];
        a0 += bflo(u0) + bflo(u1);
        a1 += bfhi(u0) + bfhi(u1);
    }
    if (i < s1) {
        unsigned int u = hss[(int)csr[i] * 16 + li];
        a0 += bflo(u); a1 += bfhi(u);
    }
    a0 += __shfl_xor(a0, 16); a0 += __shfl_xor(a0, 32);
    a1 += __shfl_xor(a1, 16); a1 += __shfl_xor(a1, 32);
    if (grp == 0) {
        unsigned int su = hss[v * 16 + li];   // self-loop
        float dv = dinv[v];
        float f0 = dv * (a0 + bflo(su)) + bc[s * 32 + 2 * li];
        float f1 = dv * (a1 + bfhi(su)) + bc[s * 32 + 2 * li + 1];
        feats[v * 16 + li] = pk2(f0, f1);
    }
}

// ---- sliced scoring: partial dot on one 3.2 MB slice, accumulate into out ----
__global__ void score_slice_k(const int* __restrict__ src, const int* __restrict__ dst,
                              const unsigned int* __restrict__ feats,
                              float* __restrict__ out, int first) {
    int gid = blockIdx.x * blockDim.x + threadIdx.x;
    int e = gid >> 4, li = gid & 15;
    if (e >= N_PRED) return;
    int a = src[e], b = dst[e];
    unsigned int ua = feats[(long)a * 16 + li];
    unsigned int ub = feats[(long)b * 16 + li];
    float p = bflo(ua) * bflo(ub) + bfhi(ua) * bfhi(ub);
    #pragma unroll
    for (int m = 8; m; m >>= 1) p += __shfl_xor(p, m, 16);
    if (li == 0) {
        if (first) out[e] = p;
        else out[e] += p;
    }
}

extern "C" void kernel_launch(void* const* d_in, const int* in_sizes, int n_in,
                              void* d_out, int out_size, void* d_ws, size_t ws_size,
                              hipStream_t stream) {
    const float* x   = (const float*)d_in[0];
    const int*   ei  = (const int*)  d_in[1];   // [2, N_PRED]
    const int*   pe  = (const int*)  d_in[2];   // [2, N_POS]
    const float* W1  = (const float*)d_in[3];
    const float* b1  = (const float*)d_in[4];
    const float* Wc  = (const float*)d_in[5];
    const float* bc  = (const float*)d_in[6];
    float* out = (float*)d_out;

    const int* pe_row = pe;            // source
    const int* pe_col = pe + N_POS;    // target (aggregation)
    const int* ei_src = ei;
    const int* ei_dst = ei + N_PRED;

    // workspace layout (16B-aligned blocks)
    char* w = (char*)d_ws;
    unsigned short* Bp = (unsigned short*)w;  w += 32768 * 2;      // 64 KB
    float* bf    = (float*)w;                 w += 128 * 4;
    float* dinv  = (float*)w;                 w += 50000 * 4;
    int*   bcnt  = (int*)w;                   w += GPAD * 4;
    int*   boffs = (int*)w;                   w += (GPAD + 4) * 4;
    int*   bfill = (int*)w;                   w += GPAD * 4;
    int*   offs  = (int*)w;                   w += 50004 * 4;      // [N+1] padded
    unsigned int* eb = (unsigned int*)w;      w += (long)N_POS * 4;              // 6.4 MB
    unsigned short* csr = (unsigned short*)w; w += (long)N_POS * 2;              // 3.2 MB
    unsigned short* hsb   = (unsigned short*)w;  w += (long)N_NODES * D_OUT * 2; // 12.8 MB sliced
    unsigned short* featb = (unsigned short*)w;  // 12.8 MB sliced

    // bucket partition of edges by target + CSR build (contiguous writes only)
    zero_int_k      <<<4, 256, 0, stream>>>(bcnt, GPAD);
    bucket_count_k  <<<SB, 256, 0, stream>>>(pe_col, bcnt);
    scan_bucket_k   <<<1, 1024, 0, stream>>>(bcnt, boffs, bfill, offs);
    bucket_scatter_k<<<SB, 256, 0, stream>>>(pe_row, pe_col, bfill, eb);
    csr_build_k     <<<G_BUCKETS, 256, 0, stream>>>(boffs, eb, csr, offs, dinv);

    // dense pipeline (MFMA, sliced hs output)
    fuse_weights_k<<<128, 256, 0, stream>>>(W1, Wc, b1, Bp, bf);
    gemm_mfma_k   <<<(N_NODES + 63) / 64, 256, 0, stream>>>(x, (const uint4*)Bp, bf, dinv, hsb);

    // sliced aggregation + finalize: 4 passes, each slice table L2-resident
    for (int s = 0; s < 4; ++s)
        aggregate_slice_k<<<N_NODES / 4, 256, 0, stream>>>(
            offs, csr, (const unsigned int*)hsb + (long)s * N_NODES * 16,
            dinv, bc, (unsigned int*)featb + (long)s * N_NODES * 16, s);

    // sliced scoring: 4 passes accumulating into out
    for (int s = 0; s < 4; ++s)
        score_slice_k<<<(int)(((long)N_PRED * 16) / 256), 256, 0, stream>>>(
            ei_src, ei_dst, (const unsigned int*)featb + (long)s * N_NODES * 16,
            out, s == 0 ? 1 : 0);
}

// Round 8
// 362.710 us; speedup vs baseline: 1.0918x; 1.0918x over previous
//
#include <hip/hip_runtime.h>

#define N_NODES 50000
#define D_IN 256
#define D_OUT 128
#define N_POS 1600000
#define N_PRED 500000

#define G_BUCKETS 782        // ceil(50000/64) buckets of 64 nodes
#define GPAD 1024
#define SB 160               // scatter blocks
#define CHUNK 10000          // SB*CHUNK == N_POS exactly
#define CAP 4096             // eb segment per bucket (mean 2048, sigma ~45)

typedef __attribute__((ext_vector_type(8))) short short8;
typedef __attribute__((ext_vector_type(4))) float f32x4;

// ---- bf16 helpers (RNE) ----
__device__ __forceinline__ unsigned short f2bf(float f) {
    unsigned int u = __float_as_uint(f);
    u += 0x7FFFu + ((u >> 16) & 1u);
    return (unsigned short)(u >> 16);
}
__device__ __forceinline__ unsigned int pk2(float a, float b) {   // bf16(a) | bf16(b)<<16
    unsigned int ua = __float_as_uint(a), ub = __float_as_uint(b);
    ua += 0x7FFFu + ((ua >> 16) & 1u);
    ub += 0x7FFFu + ((ub >> 16) & 1u);
    return (ua >> 16) | (ub & 0xFFFF0000u);
}
__device__ __forceinline__ float bflo(unsigned int u) { return __uint_as_float(u << 16); }
__device__ __forceinline__ float bfhi(unsigned int u) { return __uint_as_float(u & 0xFFFF0000u); }

// ------- Wf = W1@Wc packed into MFMA B-fragment layout; bf = b1@Wc -------
__global__ void fuse_weights_k(const float* __restrict__ W1, const float* __restrict__ Wc,
                               const float* __restrict__ b1,
                               unsigned short* __restrict__ Bp, float* __restrict__ bf) {
    int gid = blockIdx.x * blockDim.x + threadIdx.x;   // 0..32767
    int k = gid >> 7;          // K dim
    int n = gid & 127;         // N dim
    float acc = 0.f;
    #pragma unroll 4
    for (int kk = 0; kk < D_IN; ++kk)
        acc += W1[k * D_IN + kk] * Wc[kk * D_OUT + n];
    int ks = k >> 5, q = (k >> 3) & 3, jj = k & 7;
    int nt = n >> 4, nl = n & 15;
    int lane = q * 16 + nl;
    Bp[(((long)(ks * 8 + nt)) * 64 + lane) * 8 + jj] = f2bf(acc);
    if (gid < D_OUT) {
        float accb = 0.f;
        for (int kk = 0; kk < D_IN; ++kk)
            accb += b1[kk] * Wc[kk * D_OUT + gid];
        bf[gid] = accb;
    }
}

// bfill[g] = g*CAP (segment cursors)
__global__ void init_fill_k(int* __restrict__ bfill) {
    int g = blockIdx.x * blockDim.x + threadIdx.x;
    if (g < G_BUCKETS) bfill[g] = g * CAP;
}

// bin chunk edges by bucket in LDS, write bucket-contiguous bursts into eb segments
__global__ __launch_bounds__(256) void bucket_scatter_k(const int* __restrict__ row,
                                                        const int* __restrict__ col,
                                                        int* __restrict__ bfill,
                                                        unsigned int* __restrict__ eb) {
    __shared__ int hist[GPAD];
    __shared__ int lofs[GPAD];
    __shared__ int fill2[GPAD];
    __shared__ int base[GPAD];
    __shared__ int part[256];
    __shared__ unsigned int stag[CHUNK];
    int t = threadIdx.x;
    for (int i = t; i < GPAD; i += 256) { hist[i] = 0; fill2[i] = 0; }
    __syncthreads();
    int e0 = blockIdx.x * CHUNK;
    for (int i = t; i < CHUNK; i += 256)
        atomicAdd(&hist[col[e0 + i] >> 6], 1);
    __syncthreads();
    int h[4], p4 = 0;
    #pragma unroll
    for (int i = 0; i < 4; ++i) { h[i] = hist[4 * t + i]; p4 += h[i]; }
    part[t] = p4;
    __syncthreads();
    for (int d = 1; d < 256; d <<= 1) {
        int add = (t >= d) ? part[t - d] : 0;
        __syncthreads();
        part[t] += add;
        __syncthreads();
    }
    int ex = part[t] - p4;
    #pragma unroll
    for (int i = 0; i < 4; ++i) { lofs[4 * t + i] = ex; ex += h[i]; }
    __syncthreads();
    for (int g = t; g < G_BUCKETS; g += 256) {
        int c = hist[g];
        base[g] = c ? atomicAdd(&bfill[g], c) : 0;
    }
    for (int i = t; i < CHUNK; i += 256) {
        int c = col[e0 + i];
        int g = c >> 6;
        unsigned int u = (unsigned int)row[e0 + i] | ((unsigned int)(c & 63) << 16)
                       | ((unsigned int)g << 22);
        int lp = atomicAdd(&fill2[g], 1);
        stag[lofs[g] + lp] = u;
    }
    __syncthreads();
    for (int i = t; i < CHUNK; i += 256) {
        unsigned int u = stag[i];
        int g = u >> 22;
        eb[base[g] + (i - lofs[g])] = u;
    }
}

// ---- per-bucket CSR build (segmented): node-sorted ushort rows; offs/ends/dinv ----
__global__ __launch_bounds__(256) void csr_build_k(const int* __restrict__ bfill,
                                                   const unsigned int* __restrict__ eb,
                                                   unsigned short* __restrict__ csr,
                                                   int* __restrict__ offs,
                                                   int* __restrict__ ends,
                                                   float* __restrict__ dinv) {
    __shared__ unsigned int stag[CAP];
    __shared__ unsigned short stag2[CAP];
    __shared__ int hist[64], lofs[64], fill[64];
    int t = threadIdx.x;
    int g = blockIdx.x;
    int s = g * CAP;
    int cnt = bfill[g] - s;
    if (t < 64) { hist[t] = 0; fill[t] = 0; }
    __syncthreads();
    for (int i = t; i < cnt; i += 256) {
        unsigned int u = eb[s + i];
        stag[i] = u;
        atomicAdd(&hist[(u >> 16) & 63], 1);
    }
    __syncthreads();
    if (t == 0) {
        int run = 0;
        for (int k = 0; k < 64; ++k) { lofs[k] = run; run += hist[k]; }
    }
    __syncthreads();
    if (t < 64) {
        int v = g * 64 + t;
        if (v < N_NODES) {
            offs[v] = s + lofs[t];
            ends[v] = s + lofs[t] + hist[t];
            dinv[v] = rsqrtf((float)hist[t] + 1.0f);   // +1 self loop
        }
    }
    for (int i = t; i < cnt; i += 256) {
        unsigned int u = stag[i];
        int nl = (u >> 16) & 63;
        int lp = atomicAdd(&fill[nl], 1);
        stag2[lofs[nl] + lp] = (unsigned short)(u & 0xFFFF);
    }
    __syncthreads();
    for (int i = t; i < cnt; i += 256)
        csr[s + i] = stag2[i];
}

// ------- MFMA GEMM: hs[slice][node][32B] = bf16( dinv[v] * (x @ Wf + bf) ) -------
__global__ __launch_bounds__(256) void gemm_mfma_k(const float* __restrict__ x,
                                                   const uint4* __restrict__ Bp,
                                                   const float* __restrict__ bf,
                                                   const float* __restrict__ dinv,
                                                   unsigned short* __restrict__ hsb) {
    __shared__ unsigned short ot[4][16 * 128];   // 16 KB epilogue staging
    const int wave = threadIdx.x >> 6;
    const int lane = threadIdx.x & 63;
    const int q    = lane >> 4;
    const int ml   = lane & 15;
    const int m0   = blockIdx.x * 64 + wave * 16;

    f32x4 acc[8];
    #pragma unroll
    for (int t = 0; t < 8; ++t) acc[t] = (f32x4){0.f, 0.f, 0.f, 0.f};

    long arow = m0 + ml; if (arow > N_NODES - 1) arow = N_NODES - 1;
    const float* xrow = x + arow * D_IN + q * 8;

    #pragma unroll
    for (int ks = 0; ks < 8; ++ks) {
        float4 xa = *(const float4*)(xrow + ks * 32);
        float4 xb = *(const float4*)(xrow + ks * 32 + 4);
        union { short8 s; unsigned int u[4]; } af;
        af.u[0] = pk2(xa.x, xa.y);
        af.u[1] = pk2(xa.z, xa.w);
        af.u[2] = pk2(xb.x, xb.y);
        af.u[3] = pk2(xb.z, xb.w);
        #pragma unroll
        for (int nt = 0; nt < 8; ++nt) {
            union { uint4 v; short8 s; } bu;
            bu.v = Bp[(long)(ks * 8 + nt) * 64 + lane];
            acc[nt] = __builtin_amdgcn_mfma_f32_16x16x32_bf16(af.s, bu.s, acc[nt], 0, 0, 0);
        }
    }

    float dv[4];
    #pragma unroll
    for (int r = 0; r < 4; ++r) {
        int v = m0 + q * 4 + r;
        dv[r] = dinv[v > N_NODES - 1 ? N_NODES - 1 : v];
    }
    unsigned short* o = ot[wave];
    #pragma unroll
    for (int nt = 0; nt < 8; ++nt) {
        float bn = bf[nt * 16 + ml];
        #pragma unroll
        for (int r = 0; r < 4; ++r) {
            float val = dv[r] * (acc[nt][r] + bn);
            o[(q * 4 + r) * 128 + nt * 16 + ml] = f2bf(val);
        }
    }
    __syncthreads();
    // sliced store: slice s holds row bytes s*32..s*32+31 -> hsb[(s*N+v)*32 ..]
    {
        int r = lane >> 2, p = lane & 3;
        int v = m0 + r;
        if (v < N_NODES) {
            #pragma unroll
            for (int ss = 0; ss < 4; ++ss) {
                int fb = ss * 64 + p * 16;          // byte within the 256B row
                int sl = fb >> 5;                   // slice 0..7
                uint4 val = *(const uint4*)((const char*)o + r * 256 + fb);
                *(uint4*)((char*)hsb + ((long)sl * N_NODES + v) * 32 + (fb & 31)) = val;
            }
        }
    }
}

// ---- XCD-affine sliced aggregation: slice = blockIdx&7; table slice = 1.6 MB ----
// wave = 1 (node, slice): 8 groups x 8 lanes; lane li owns uint li of the 8-uint row.
__global__ __launch_bounds__(256) void aggregate_slice_k(const int* __restrict__ offs,
                                                         const int* __restrict__ ends,
                                                         const unsigned short* __restrict__ csr,
                                                         const unsigned int* __restrict__ hsb,
                                                         const float* __restrict__ dinv,
                                                         const float* __restrict__ bc,
                                                         unsigned int* __restrict__ featb) {
    int b  = blockIdx.x;
    int sl = b & 7;
    int v  = (b >> 3) * 4 + (threadIdx.x >> 6);
    int lane = threadIdx.x & 63;
    int grp = lane >> 3, li = lane & 7;
    const unsigned int* tab = hsb + (long)sl * N_NODES * 8;

    int s0 = offs[v], s1 = ends[v];
    float a0 = 0.f, a1 = 0.f;
    int i = s0 + grp;
    for (; i + 8 < s1; i += 16) {
        int r0 = csr[i], r1 = csr[i + 8];
        unsigned int u0 = tab[r0 * 8 + li];
        unsigned int u1 = tab[r1 * 8 + li];
        a0 += bflo(u0) + bflo(u1);
        a1 += bfhi(u0) + bfhi(u1);
    }
    if (i < s1) {
        unsigned int u = tab[(int)csr[i] * 8 + li];
        a0 += bflo(u); a1 += bfhi(u);
    }
    a0 += __shfl_xor(a0, 8); a0 += __shfl_xor(a0, 16); a0 += __shfl_xor(a0, 32);
    a1 += __shfl_xor(a1, 8); a1 += __shfl_xor(a1, 16); a1 += __shfl_xor(a1, 32);
    if (grp == 0) {
        unsigned int su = tab[v * 8 + li];   // self-loop
        float dv = dinv[v];
        float f0 = dv * (a0 + bflo(su)) + bc[sl * 16 + 2 * li];
        float f1 = dv * (a1 + bfhi(su)) + bc[sl * 16 + 2 * li + 1];
        featb[(long)sl * N_NODES * 8 + v * 8 + li] = pk2(f0, f1);
    }
}

// ---- XCD-affine sliced scoring: partials into out_part[slice][e] ----
#define EPB 512
__global__ __launch_bounds__(256) void score_slice_k(const int* __restrict__ src,
                                                     const int* __restrict__ dst,
                                                     const unsigned int* __restrict__ featb,
                                                     float* __restrict__ out_part) {
    int b  = blockIdx.x;
    int sl = b & 7;
    int chunk = b >> 3;
    const unsigned int* tab = featb + (long)sl * N_NODES * 8;
    int slot = threadIdx.x >> 3, li = threadIdx.x & 7;
    #pragma unroll
    for (int t = 0; t < EPB / 32; ++t) {
        int e = chunk * EPB + t * 32 + slot;
        if (e < N_PRED) {
            int a = src[e], d = dst[e];
            unsigned int ua = tab[a * 8 + li];
            unsigned int ub = tab[d * 8 + li];
            float p = bflo(ua) * bflo(ub) + bfhi(ua) * bfhi(ub);
            p += __shfl_xor(p, 1); p += __shfl_xor(p, 2); p += __shfl_xor(p, 4);
            if (li == 0) out_part[(long)sl * N_PRED + e] = p;
        }
    }
}

__global__ void reduce_out_k(const float* __restrict__ out_part, float* __restrict__ out) {
    int e = blockIdx.x * blockDim.x + threadIdx.x;
    if (e >= N_PRED) return;
    float r = 0.f;
    #pragma unroll
    for (int s = 0; s < 8; ++s) r += out_part[(long)s * N_PRED + e];
    out[e] = r;
}

extern "C" void kernel_launch(void* const* d_in, const int* in_sizes, int n_in,
                              void* d_out, int out_size, void* d_ws, size_t ws_size,
                              hipStream_t stream) {
    const float* x   = (const float*)d_in[0];
    const int*   ei  = (const int*)  d_in[1];   // [2, N_PRED]
    const int*   pe  = (const int*)  d_in[2];   // [2, N_POS]
    const float* W1  = (const float*)d_in[3];
    const float* b1  = (const float*)d_in[4];
    const float* Wc  = (const float*)d_in[5];
    const float* bc  = (const float*)d_in[6];
    float* out = (float*)d_out;

    const int* pe_row = pe;            // source
    const int* pe_col = pe + N_POS;    // target (aggregation)
    const int* ei_src = ei;
    const int* ei_dst = ei + N_PRED;

    // workspace layout (16B-aligned blocks)
    char* w = (char*)d_ws;
    unsigned short* Bp = (unsigned short*)w;  w += 32768 * 2;      // 64 KB
    float* bf    = (float*)w;                 w += 128 * 4;
    float* dinv  = (float*)w;                 w += 50000 * 4;
    int*   bfill = (int*)w;                   w += GPAD * 4;
    int*   offs  = (int*)w;                   w += 50000 * 4;
    int*   ends  = (int*)w;                   w += 50000 * 4;
    char* ebbase = w;
    unsigned int* eb = (unsigned int*)w;      w += (long)G_BUCKETS * CAP * 4;    // 12.81 MB
    unsigned short* csr = (unsigned short*)w; w += (long)G_BUCKETS * CAP * 2;    // 6.4 MB
    unsigned short* hsb   = (unsigned short*)w;  w += (long)N_NODES * D_OUT * 2; // 12.8 MB sliced
    unsigned short* featb = (unsigned short*)w;  w += (long)N_NODES * D_OUT * 2; // 12.8 MB sliced
    float* out_part = (float*)ebbase;         // 16 MB, aliases eb+csr (dead by score time)

    // edge partition into per-bucket segments + segmented CSR build
    init_fill_k     <<<4, 256, 0, stream>>>(bfill);
    bucket_scatter_k<<<SB, 256, 0, stream>>>(pe_row, pe_col, bfill, eb);
    csr_build_k     <<<G_BUCKETS, 256, 0, stream>>>(bfill, eb, csr, offs, ends, dinv);

    // dense pipeline (MFMA, sliced hs output)
    fuse_weights_k<<<128, 256, 0, stream>>>(W1, Wc, b1, Bp, bf);
    gemm_mfma_k   <<<(N_NODES + 63) / 64, 256, 0, stream>>>(x, (const uint4*)Bp, bf, dinv, hsb);

    // XCD-affine aggregation + finalize (single launch, slice = blockIdx&7)
    aggregate_slice_k<<<(N_NODES / 4) * 8, 256, 0, stream>>>(
        offs, ends, csr, (const unsigned int*)hsb, dinv, bc, (unsigned int*)featb);

    // XCD-affine scoring + reduce
    score_slice_k<<<((N_PRED + EPB - 1) / EPB) * 8, 256, 0, stream>>>(
        ei_src, ei_dst, (const unsigned int*)featb, out_part);
    reduce_out_k <<<(N_PRED + 255) / 256, 256, 0, stream>>>(out_part, out);
}

// Round 9
// 279.226 us; speedup vs baseline: 1.4182x; 1.2990x over previous
//
#include <hip/hip_runtime.h>

#define N_NODES 50000
#define D_IN 256
#define D_OUT 128
#define N_POS 1600000
#define N_PRED 500000

#define G_BUCKETS 782        // ceil(50000/64) buckets of 64 nodes
#define GPAD 1024
#define SB 160               // scatter blocks
#define CHUNK 10000          // SB*CHUNK == N_POS exactly
#define CAP 4096             // eb segment per bucket (mean 2048, sigma ~45)

typedef __attribute__((ext_vector_type(8))) short short8;
typedef __attribute__((ext_vector_type(4))) float f32x4;

// ---- bf16 helpers (RNE) ----
__device__ __forceinline__ unsigned short f2bf(float f) {
    unsigned int u = __float_as_uint(f);
    u += 0x7FFFu + ((u >> 16) & 1u);
    return (unsigned short)(u >> 16);
}
__device__ __forceinline__ unsigned int pk2(float a, float b) {   // bf16(a) | bf16(b)<<16
    unsigned int ua = __float_as_uint(a), ub = __float_as_uint(b);
    ua += 0x7FFFu + ((ua >> 16) & 1u);
    ub += 0x7FFFu + ((ub >> 16) & 1u);
    return (ua >> 16) | (ub & 0xFFFF0000u);
}
__device__ __forceinline__ float bflo(unsigned int u) { return __uint_as_float(u << 16); }
__device__ __forceinline__ float bfhi(unsigned int u) { return __uint_as_float(u & 0xFFFF0000u); }

// ------- Wf = W1@Wc packed into MFMA B-fragment layout; bf = b1@Wc -------
__global__ void fuse_weights_k(const float* __restrict__ W1, const float* __restrict__ Wc,
                               const float* __restrict__ b1,
                               unsigned short* __restrict__ Bp, float* __restrict__ bf) {
    int gid = blockIdx.x * blockDim.x + threadIdx.x;   // 0..32767
    int k = gid >> 7;          // K dim
    int n = gid & 127;         // N dim
    float acc = 0.f;
    #pragma unroll 4
    for (int kk = 0; kk < D_IN; ++kk)
        acc += W1[k * D_IN + kk] * Wc[kk * D_OUT + n];
    int ks = k >> 5, q = (k >> 3) & 3, jj = k & 7;
    int nt = n >> 4, nl = n & 15;
    int lane = q * 16 + nl;
    Bp[(((long)(ks * 8 + nt)) * 64 + lane) * 8 + jj] = f2bf(acc);
    if (gid < D_OUT) {
        float accb = 0.f;
        for (int kk = 0; kk < D_IN; ++kk)
            accb += b1[kk] * Wc[kk * D_OUT + gid];
        bf[gid] = accb;
    }
}

// bfill[g] = g*CAP (segment cursors)
__global__ void init_fill_k(int* __restrict__ bfill) {
    int g = blockIdx.x * blockDim.x + threadIdx.x;
    if (g < G_BUCKETS) bfill[g] = g * CAP;
}

// bin chunk edges by bucket in LDS, write bucket-contiguous bursts into eb segments
__global__ __launch_bounds__(256) void bucket_scatter_k(const int* __restrict__ row,
                                                        const int* __restrict__ col,
                                                        int* __restrict__ bfill,
                                                        unsigned int* __restrict__ eb) {
    __shared__ int hist[GPAD];
    __shared__ int lofs[GPAD];
    __shared__ int fill2[GPAD];
    __shared__ int base[GPAD];
    __shared__ int part[256];
    __shared__ unsigned int stag[CHUNK];
    int t = threadIdx.x;
    for (int i = t; i < GPAD; i += 256) { hist[i] = 0; fill2[i] = 0; }
    __syncthreads();
    int e0 = blockIdx.x * CHUNK;
    for (int i = t; i < CHUNK; i += 256)
        atomicAdd(&hist[col[e0 + i] >> 6], 1);
    __syncthreads();
    int h[4], p4 = 0;
    #pragma unroll
    for (int i = 0; i < 4; ++i) { h[i] = hist[4 * t + i]; p4 += h[i]; }
    part[t] = p4;
    __syncthreads();
    for (int d = 1; d < 256; d <<= 1) {
        int add = (t >= d) ? part[t - d] : 0;
        __syncthreads();
        part[t] += add;
        __syncthreads();
    }
    int ex = part[t] - p4;
    #pragma unroll
    for (int i = 0; i < 4; ++i) { lofs[4 * t + i] = ex; ex += h[i]; }
    __syncthreads();
    for (int g = t; g < G_BUCKETS; g += 256) {
        int c = hist[g];
        base[g] = c ? atomicAdd(&bfill[g], c) : 0;
    }
    for (int i = t; i < CHUNK; i += 256) {
        int c = col[e0 + i];
        int g = c >> 6;
        unsigned int u = (unsigned int)row[e0 + i] | ((unsigned int)(c & 63) << 16)
                       | ((unsigned int)g << 22);
        int lp = atomicAdd(&fill2[g], 1);
        stag[lofs[g] + lp] = u;
    }
    __syncthreads();
    for (int i = t; i < CHUNK; i += 256) {
        unsigned int u = stag[i];
        int g = u >> 22;
        eb[base[g] + (i - lofs[g])] = u;
    }
}

// ---- per-bucket CSR build (segmented): node-sorted ushort rows; offs/ends/dinv ----
__global__ __launch_bounds__(256) void csr_build_k(const int* __restrict__ bfill,
                                                   const unsigned int* __restrict__ eb,
                                                   unsigned short* __restrict__ csr,
                                                   int* __restrict__ offs,
                                                   int* __restrict__ ends,
                                                   float* __restrict__ dinv) {
    __shared__ unsigned int stag[CAP];
    __shared__ unsigned short stag2[CAP];
    __shared__ int hist[64], lofs[64], fill[64];
    int t = threadIdx.x;
    int g = blockIdx.x;
    int s = g * CAP;
    int cnt = bfill[g] - s;
    if (t < 64) { hist[t] = 0; fill[t] = 0; }
    __syncthreads();
    for (int i = t; i < cnt; i += 256) {
        unsigned int u = eb[s + i];
        stag[i] = u;
        atomicAdd(&hist[(u >> 16) & 63], 1);
    }
    __syncthreads();
    if (t == 0) {
        int run = 0;
        for (int k = 0; k < 64; ++k) { lofs[k] = run; run += hist[k]; }
    }
    __syncthreads();
    if (t < 64) {
        int v = g * 64 + t;
        if (v < N_NODES) {
            offs[v] = s + lofs[t];
            ends[v] = s + lofs[t] + hist[t];
            dinv[v] = rsqrtf((float)hist[t] + 1.0f);   // +1 self loop
        }
    }
    for (int i = t; i < cnt; i += 256) {
        unsigned int u = stag[i];
        int nl = (u >> 16) & 63;
        int lp = atomicAdd(&fill[nl], 1);
        stag2[lofs[nl] + lp] = (unsigned short)(u & 0xFFFF);
    }
    __syncthreads();
    for (int i = t; i < cnt; i += 256)
        csr[s + i] = stag2[i];
}

// ------- MFMA GEMM: hs = bf16( dinv[v] * (x @ Wf + bf) ), row-major 256 B rows -------
__global__ __launch_bounds__(256) void gemm_mfma_k(const float* __restrict__ x,
                                                   const uint4* __restrict__ Bp,
                                                   const float* __restrict__ bf,
                                                   const float* __restrict__ dinv,
                                                   unsigned short* __restrict__ hsb) {
    __shared__ unsigned short ot[4][16 * 128];   // 16 KB epilogue staging
    const int wave = threadIdx.x >> 6;
    const int lane = threadIdx.x & 63;
    const int q    = lane >> 4;
    const int ml   = lane & 15;
    const int m0   = blockIdx.x * 64 + wave * 16;

    f32x4 acc[8];
    #pragma unroll
    for (int t = 0; t < 8; ++t) acc[t] = (f32x4){0.f, 0.f, 0.f, 0.f};

    long arow = m0 + ml; if (arow > N_NODES - 1) arow = N_NODES - 1;
    const float* xrow = x + arow * D_IN + q * 8;

    #pragma unroll
    for (int ks = 0; ks < 8; ++ks) {
        float4 xa = *(const float4*)(xrow + ks * 32);
        float4 xb = *(const float4*)(xrow + ks * 32 + 4);
        union { short8 s; unsigned int u[4]; } af;
        af.u[0] = pk2(xa.x, xa.y);
        af.u[1] = pk2(xa.z, xa.w);
        af.u[2] = pk2(xb.x, xb.y);
        af.u[3] = pk2(xb.z, xb.w);
        #pragma unroll
        for (int nt = 0; nt < 8; ++nt) {
            union { uint4 v; short8 s; } bu;
            bu.v = Bp[(long)(ks * 8 + nt) * 64 + lane];
            acc[nt] = __builtin_amdgcn_mfma_f32_16x16x32_bf16(af.s, bu.s, acc[nt], 0, 0, 0);
        }
    }

    float dv[4];
    #pragma unroll
    for (int r = 0; r < 4; ++r) {
        int v = m0 + q * 4 + r;
        dv[r] = dinv[v > N_NODES - 1 ? N_NODES - 1 : v];
    }
    unsigned short* o = ot[wave];
    #pragma unroll
    for (int nt = 0; nt < 8; ++nt) {
        float bn = bf[nt * 16 + ml];
        #pragma unroll
        for (int r = 0; r < 4; ++r) {
            float val = dv[r] * (acc[nt][r] + bn);
            o[(q * 4 + r) * 128 + nt * 16 + ml] = f2bf(val);
        }
    }
    __syncthreads();
    #pragma unroll
    for (int i = 0; i < 4; ++i) {
        int fb = i * 1024 + lane * 16;
        int v = m0 + (fb >> 8);
        if (v < N_NODES) {
            uint4 val = *(const uint4*)((const char*)o + fb);
            *(uint4*)((char*)hsb + (long)v * 256 + (fb & 255)) = val;
        }
    }
}

// ---- per-node aggregation: 16 lanes/edge x uint4 (16 B/lane), 4 edges in flight ----
// wave = 1 node; grp = lane>>4 owns edges i = s0+grp (mod 4); li = lane&15 owns 16 B.
__global__ __launch_bounds__(256) void aggregate_csr_k(const int* __restrict__ offs,
                                                       const int* __restrict__ ends,
                                                       const unsigned short* __restrict__ csr,
                                                       const uint4* __restrict__ hs4,
                                                       const float* __restrict__ dinv,
                                                       const float* __restrict__ bc,
                                                       uint4* __restrict__ feat4) {
    int v    = blockIdx.x * 4 + (threadIdx.x >> 6);
    int lane = threadIdx.x & 63;
    int grp  = lane >> 4, li = lane & 15;
    int s0 = offs[v], s1 = ends[v];

    float a[8] = {0.f, 0.f, 0.f, 0.f, 0.f, 0.f, 0.f, 0.f};
    int i = s0 + grp;
    for (; i + 4 < s1; i += 8) {              // 8 edges per wave iteration
        int r0 = csr[i], r1 = csr[i + 4];
        uint4 u0 = hs4[r0 * 16 + li];
        uint4 u1 = hs4[r1 * 16 + li];
        a[0] += bflo(u0.x) + bflo(u1.x);  a[1] += bfhi(u0.x) + bfhi(u1.x);
        a[2] += bflo(u0.y) + bflo(u1.y);  a[3] += bfhi(u0.y) + bfhi(u1.y);
        a[4] += bflo(u0.z) + bflo(u1.z);  a[5] += bfhi(u0.z) + bfhi(u1.z);
        a[6] += bflo(u0.w) + bflo(u1.w);  a[7] += bfhi(u0.w) + bfhi(u1.w);
    }
    if (i < s1) {
        uint4 u = hs4[(int)csr[i] * 16 + li];
        a[0] += bflo(u.x); a[1] += bfhi(u.x);
        a[2] += bflo(u.y); a[3] += bfhi(u.y);
        a[4] += bflo(u.z); a[5] += bfhi(u.z);
        a[6] += bflo(u.w); a[7] += bfhi(u.w);
    }
    // reduce across the 4 groups (lane bits 4,5)
    #pragma unroll
    for (int j = 0; j < 8; ++j) {
        a[j] += __shfl_xor(a[j], 16);
        a[j] += __shfl_xor(a[j], 32);
    }
    if (grp == 0) {
        uint4 su = hs4[v * 16 + li];           // self-loop term
        float dv = dinv[v];
        float4 b0 = *(const float4*)(bc + li * 8);
        float4 b1 = *(const float4*)(bc + li * 8 + 4);
        float f0 = dv * (a[0] + bflo(su.x)) + b0.x;
        float f1 = dv * (a[1] + bfhi(su.x)) + b0.y;
        float f2 = dv * (a[2] + bflo(su.y)) + b0.z;
        float f3 = dv * (a[3] + bfhi(su.y)) + b0.w;
        float f4 = dv * (a[4] + bflo(su.z)) + b1.x;
        float f5 = dv * (a[5] + bfhi(su.z)) + b1.y;
        float f6 = dv * (a[6] + bflo(su.w)) + b1.z;
        float f7 = dv * (a[7] + bfhi(su.w)) + b1.w;
        uint4 o;
        o.x = pk2(f0, f1); o.y = pk2(f2, f3); o.z = pk2(f4, f5); o.w = pk2(f6, f7);
        feat4[v * 16 + li] = o;
    }
}

// ---------------- logits[e] = dot(feat[src], feat[dst]) — 16 lanes/edge ----------------
__global__ void score_k(const int* __restrict__ src, const int* __restrict__ dst,
                        const uint4* __restrict__ feat4, float* __restrict__ out) {
    int gid = blockIdx.x * blockDim.x + threadIdx.x;
    int e = gid >> 4;
    int c = gid & 15;
    if (e >= N_PRED) return;
    int a = src[e], b = dst[e];
    uint4 ua = feat4[(long)a * 16 + c];
    uint4 ub = feat4[(long)b * 16 + c];
    float p = bflo(ua.x) * bflo(ub.x) + bfhi(ua.x) * bfhi(ub.x)
            + bflo(ua.y) * bflo(ub.y) + bfhi(ua.y) * bfhi(ub.y)
            + bflo(ua.z) * bflo(ub.z) + bfhi(ua.z) * bfhi(ub.z)
            + bflo(ua.w) * bflo(ub.w) + bfhi(ua.w) * bfhi(ub.w);
    #pragma unroll
    for (int m = 8; m; m >>= 1) p += __shfl_xor(p, m, 16);
    if (c == 0) out[e] = p;
}

extern "C" void kernel_launch(void* const* d_in, const int* in_sizes, int n_in,
                              void* d_out, int out_size, void* d_ws, size_t ws_size,
                              hipStream_t stream) {
    const float* x   = (const float*)d_in[0];
    const int*   ei  = (const int*)  d_in[1];   // [2, N_PRED]
    const int*   pe  = (const int*)  d_in[2];   // [2, N_POS]
    const float* W1  = (const float*)d_in[3];
    const float* b1  = (const float*)d_in[4];
    const float* Wc  = (const float*)d_in[5];
    const float* bc  = (const float*)d_in[6];
    float* out = (float*)d_out;

    const int* pe_row = pe;            // source
    const int* pe_col = pe + N_POS;    // target (aggregation)
    const int* ei_src = ei;
    const int* ei_dst = ei + N_PRED;

    // workspace layout (16B-aligned blocks)
    char* w = (char*)d_ws;
    unsigned short* Bp = (unsigned short*)w;  w += 32768 * 2;      // 64 KB
    float* bf    = (float*)w;                 w += 128 * 4;
    float* dinv  = (float*)w;                 w += 50000 * 4;
    int*   bfill = (int*)w;                   w += GPAD * 4;
    int*   offs  = (int*)w;                   w += 50000 * 4;
    int*   ends  = (int*)w;                   w += 50000 * 4;
    unsigned int* eb = (unsigned int*)w;      w += (long)G_BUCKETS * CAP * 4;    // 12.81 MB
    unsigned short* csr = (unsigned short*)w; w += (long)G_BUCKETS * CAP * 2;    // 6.4 MB
    unsigned short* hsb   = (unsigned short*)w;  w += (long)N_NODES * D_OUT * 2; // 12.8 MB
    unsigned short* featb = (unsigned short*)w;  // 12.8 MB

    // edge partition into per-bucket segments + segmented CSR build
    init_fill_k     <<<4, 256, 0, stream>>>(bfill);
    bucket_scatter_k<<<SB, 256, 0, stream>>>(pe_row, pe_col, bfill, eb);
    csr_build_k     <<<G_BUCKETS, 256, 0, stream>>>(bfill, eb, csr, offs, ends, dinv);

    // dense pipeline (MFMA)
    fuse_weights_k<<<128, 256, 0, stream>>>(W1, Wc, b1, Bp, bf);
    gemm_mfma_k   <<<(N_NODES + 63) / 64, 256, 0, stream>>>(x, (const uint4*)Bp, bf, dinv, hsb);

    // aggregation + finalize (wide gathers: 16 B/lane)
    aggregate_csr_k<<<N_NODES / 4, 256, 0, stream>>>(offs, ends, csr, (const uint4*)hsb,
                                                     dinv, bc, (uint4*)featb);

    // scoring
    score_k       <<<(int)(((long)N_PRED * 16) / 256), 256, 0, stream>>>(
                      ei_src, ei_dst, (const uint4*)featb, out);
}

// Round 10
// 267.811 us; speedup vs baseline: 1.4787x; 1.0426x over previous
//
#include <hip/hip_runtime.h>

#define N_NODES 50000
#define D_IN 256
#define D_OUT 128
#define N_POS 1600000
#define N_PRED 500000

#define G_BUCKETS 782        // ceil(50000/64) buckets of 64 nodes
#define GPAD 1024
#define SB 640               // scatter blocks
#define CHUNK 2500           // SB*CHUNK == N_POS exactly
#define CAP 4096             // eb segment per bucket (mean 2048, sigma ~45)
#define GEMM_BLOCKS 782      // (N_NODES+63)/64

typedef __attribute__((ext_vector_type(8))) short short8;
typedef __attribute__((ext_vector_type(4))) float f32x4;

// ---- bf16 helpers (RNE) ----
__device__ __forceinline__ unsigned short f2bf(float f) {
    unsigned int u = __float_as_uint(f);
    u += 0x7FFFu + ((u >> 16) & 1u);
    return (unsigned short)(u >> 16);
}
__device__ __forceinline__ unsigned int pk2(float a, float b) {   // bf16(a) | bf16(b)<<16
    unsigned int ua = __float_as_uint(a), ub = __float_as_uint(b);
    ua += 0x7FFFu + ((ua >> 16) & 1u);
    ub += 0x7FFFu + ((ub >> 16) & 1u);
    return (ua >> 16) | (ub & 0xFFFF0000u);
}
__device__ __forceinline__ float bflo(unsigned int u) { return __uint_as_float(u << 16); }
__device__ __forceinline__ float bfhi(unsigned int u) { return __uint_as_float(u & 0xFFFF0000u); }

// ------- Wf = W1@Wc packed into MFMA B-frag layout; bf = b1@Wc; block 128 inits bfill -------
__global__ void fuse_weights_k(const float* __restrict__ W1, const float* __restrict__ Wc,
                               const float* __restrict__ b1,
                               unsigned short* __restrict__ Bp, float* __restrict__ bf,
                               int* __restrict__ bfill) {
    if (blockIdx.x == 128) {           // segment-cursor init role
        for (int g = threadIdx.x; g < G_BUCKETS; g += 256) bfill[g] = g * CAP;
        return;
    }
    int gid = blockIdx.x * blockDim.x + threadIdx.x;   // 0..32767
    int k = gid >> 7;          // K dim
    int n = gid & 127;         // N dim
    float acc = 0.f;
    #pragma unroll 4
    for (int kk = 0; kk < D_IN; ++kk)
        acc += W1[k * D_IN + kk] * Wc[kk * D_OUT + n];
    int ks = k >> 5, q = (k >> 3) & 3, jj = k & 7;
    int nt = n >> 4, nl = n & 15;
    int lane = q * 16 + nl;
    Bp[(((long)(ks * 8 + nt)) * 64 + lane) * 8 + jj] = f2bf(acc);
    if (gid < D_OUT) {
        float accb = 0.f;
        for (int kk = 0; kk < D_IN; ++kk)
            accb += b1[kk] * Wc[kk * D_OUT + gid];
        bf[gid] = accb;
    }
}

// ------- fused launch: blocks [0,782) MFMA gemm (h = x@Wf+bf, UNscaled);
//         blocks [782, 782+640) bucket scatter into eb segments -------
__global__ __launch_bounds__(256) void scatter_gemm_k(const int* __restrict__ row,
                                                      const int* __restrict__ col,
                                                      int* __restrict__ bfill,
                                                      unsigned int* __restrict__ eb,
                                                      const float* __restrict__ x,
                                                      const uint4* __restrict__ Bp,
                                                      const float* __restrict__ bf,
                                                      unsigned short* __restrict__ hsb) {
    __shared__ __align__(16) char smem[27456];
    if (blockIdx.x < GEMM_BLOCKS) {
        // ---------------- gemm role ----------------
        const int wave = threadIdx.x >> 6;
        const int lane = threadIdx.x & 63;
        const int q    = lane >> 4;
        const int ml   = lane & 15;
        const int m0   = blockIdx.x * 64 + wave * 16;

        f32x4 acc[8];
        #pragma unroll
        for (int t = 0; t < 8; ++t) acc[t] = (f32x4){0.f, 0.f, 0.f, 0.f};

        long arow = m0 + ml; if (arow > N_NODES - 1) arow = N_NODES - 1;
        const float* xrow = x + arow * D_IN + q * 8;

        #pragma unroll
        for (int ks = 0; ks < 8; ++ks) {
            float4 xa = *(const float4*)(xrow + ks * 32);
            float4 xb = *(const float4*)(xrow + ks * 32 + 4);
            union { short8 s; unsigned int u[4]; } af;
            af.u[0] = pk2(xa.x, xa.y);
            af.u[1] = pk2(xa.z, xa.w);
            af.u[2] = pk2(xb.x, xb.y);
            af.u[3] = pk2(xb.z, xb.w);
            #pragma unroll
            for (int nt = 0; nt < 8; ++nt) {
                union { uint4 v; short8 s; } bu;
                bu.v = Bp[(long)(ks * 8 + nt) * 64 + lane];
                acc[nt] = __builtin_amdgcn_mfma_f32_16x16x32_bf16(af.s, bu.s, acc[nt], 0, 0, 0);
            }
        }

        unsigned short* o = (unsigned short*)smem + wave * 2048;
        #pragma unroll
        for (int nt = 0; nt < 8; ++nt) {
            float bn = bf[nt * 16 + ml];
            #pragma unroll
            for (int r = 0; r < 4; ++r) {
                float val = acc[nt][r] + bn;           // NO dinv here (decoupled)
                o[(q * 4 + r) * 128 + nt * 16 + ml] = f2bf(val);
            }
        }
        __syncthreads();
        #pragma unroll
        for (int i = 0; i < 4; ++i) {
            int fb = i * 1024 + lane * 16;
            int v = m0 + (fb >> 8);
            if (v < N_NODES) {
                uint4 val = *(const uint4*)((const char*)o + fb);
                *(uint4*)((char*)hsb + (long)v * 256 + (fb & 255)) = val;
            }
        }
    } else {
        // ---------------- scatter role ----------------
        int* hist  = (int*)smem;                 // 1024
        int* lofs  = hist + GPAD;                // 1024
        int* fill2 = lofs + GPAD;                // 1024
        int* base  = fill2 + GPAD;               // 1024
        int* part  = base + GPAD;                // 256
        unsigned int* stag = (unsigned int*)(part + 256);   // 2500
        int t = threadIdx.x;
        for (int i = t; i < GPAD; i += 256) { hist[i] = 0; fill2[i] = 0; }
        __syncthreads();
        int e0 = (blockIdx.x - GEMM_BLOCKS) * CHUNK;
        for (int i = t; i < CHUNK; i += 256)
            atomicAdd(&hist[col[e0 + i] >> 6], 1);
        __syncthreads();
        int h[4], p4 = 0;
        #pragma unroll
        for (int i = 0; i < 4; ++i) { h[i] = hist[4 * t + i]; p4 += h[i]; }
        part[t] = p4;
        __syncthreads();
        for (int d = 1; d < 256; d <<= 1) {
            int add = (t >= d) ? part[t - d] : 0;
            __syncthreads();
            part[t] += add;
            __syncthreads();
        }
        int ex = part[t] - p4;
        #pragma unroll
        for (int i = 0; i < 4; ++i) { lofs[4 * t + i] = ex; ex += h[i]; }
        __syncthreads();
        for (int g = t; g < G_BUCKETS; g += 256) {
            int c = hist[g];
            base[g] = c ? atomicAdd(&bfill[g], c) : 0;
        }
        for (int i = t; i < CHUNK; i += 256) {
            int c = col[e0 + i];
            int g = c >> 6;
            unsigned int u = (unsigned int)row[e0 + i] | ((unsigned int)(c & 63) << 16)
                           | ((unsigned int)g << 22);
            int lp = atomicAdd(&fill2[g], 1);
            stag[lofs[g] + lp] = u;
        }
        __syncthreads();
        for (int i = t; i < CHUNK; i += 256) {
            unsigned int u = stag[i];
            int g = u >> 22;
            eb[base[g] + (i - lofs[g])] = u;
        }
    }
}

// ---- per-bucket CSR build (segmented): node-sorted ushort rows; offs/ends/dinv ----
__global__ __launch_bounds__(256) void csr_build_k(const int* __restrict__ bfill,
                                                   const unsigned int* __restrict__ eb,
                                                   unsigned short* __restrict__ csr,
                                                   int* __restrict__ offs,
                                                   int* __restrict__ ends,
                                                   float* __restrict__ dinv) {
    __shared__ unsigned int stag[CAP];
    __shared__ unsigned short stag2[CAP];
    __shared__ int hist[64], lofs[64], fill[64];
    int t = threadIdx.x;
    int g = blockIdx.x;
    int s = g * CAP;
    int cnt = bfill[g] - s;
    if (t < 64) { hist[t] = 0; fill[t] = 0; }
    __syncthreads();
    for (int i = t; i < cnt; i += 256) {
        unsigned int u = eb[s + i];
        stag[i] = u;
        atomicAdd(&hist[(u >> 16) & 63], 1);
    }
    __syncthreads();
    if (t == 0) {
        int run = 0;
        for (int k = 0; k < 64; ++k) { lofs[k] = run; run += hist[k]; }
    }
    __syncthreads();
    if (t < 64) {
        int v = g * 64 + t;
        if (v < N_NODES) {
            offs[v] = s + lofs[t];
            ends[v] = s + lofs[t] + hist[t];
            dinv[v] = rsqrtf((float)hist[t] + 1.0f);   // +1 self loop
        }
    }
    for (int i = t; i < cnt; i += 256) {
        unsigned int u = stag[i];
        int nl = (u >> 16) & 63;
        int lp = atomicAdd(&fill[nl], 1);
        stag2[lofs[nl] + lp] = (unsigned short)(u & 0xFFFF);
    }
    __syncthreads();
    for (int i = t; i < cnt; i += 256)
        csr[s + i] = stag2[i];
}

// ---- per-node aggregation with on-the-fly dinv[r] scaling; 16 lanes/edge x uint4 ----
__global__ __launch_bounds__(256) void aggregate_csr_k(const int* __restrict__ offs,
                                                       const int* __restrict__ ends,
                                                       const unsigned short* __restrict__ csr,
                                                       const uint4* __restrict__ hs4,
                                                       const float* __restrict__ dinv,
                                                       const float* __restrict__ bc,
                                                       uint4* __restrict__ feat4) {
    int v    = blockIdx.x * 4 + (threadIdx.x >> 6);
    int lane = threadIdx.x & 63;
    int grp  = lane >> 4, li = lane & 15;
    int s0 = offs[v], s1 = ends[v];

    float a[8] = {0.f, 0.f, 0.f, 0.f, 0.f, 0.f, 0.f, 0.f};
    int i = s0 + grp;
    for (; i + 4 < s1; i += 8) {              // 8 edges per wave iteration
        int r0 = csr[i], r1 = csr[i + 4];
        uint4 u0 = hs4[r0 * 16 + li];
        uint4 u1 = hs4[r1 * 16 + li];
        float d0 = dinv[r0], d1 = dinv[r1];   // 4B broadcast loads (L1)
        a[0] = fmaf(d0, bflo(u0.x), a[0]); a[0] = fmaf(d1, bflo(u1.x), a[0]);
        a[1] = fmaf(d0, bfhi(u0.x), a[1]); a[1] = fmaf(d1, bfhi(u1.x), a[1]);
        a[2] = fmaf(d0, bflo(u0.y), a[2]); a[2] = fmaf(d1, bflo(u1.y), a[2]);
        a[3] = fmaf(d0, bfhi(u0.y), a[3]); a[3] = fmaf(d1, bfhi(u1.y), a[3]);
        a[4] = fmaf(d0, bflo(u0.z), a[4]); a[4] = fmaf(d1, bflo(u1.z), a[4]);
        a[5] = fmaf(d0, bfhi(u0.z), a[5]); a[5] = fmaf(d1, bfhi(u1.z), a[5]);
        a[6] = fmaf(d0, bflo(u0.w), a[6]); a[6] = fmaf(d1, bflo(u1.w), a[6]);
        a[7] = fmaf(d0, bfhi(u0.w), a[7]); a[7] = fmaf(d1, bfhi(u1.w), a[7]);
    }
    if (i < s1) {
        int r = csr[i];
        uint4 u = hs4[r * 16 + li];
        float d = dinv[r];
        a[0] = fmaf(d, bflo(u.x), a[0]); a[1] = fmaf(d, bfhi(u.x), a[1]);
        a[2] = fmaf(d, bflo(u.y), a[2]); a[3] = fmaf(d, bfhi(u.y), a[3]);
        a[4] = fmaf(d, bflo(u.z), a[4]); a[5] = fmaf(d, bfhi(u.z), a[5]);
        a[6] = fmaf(d, bflo(u.w), a[6]); a[7] = fmaf(d, bfhi(u.w), a[7]);
    }
    // reduce across the 4 groups (lane bits 4,5)
    #pragma unroll
    for (int j = 0; j < 8; ++j) {
        a[j] += __shfl_xor(a[j], 16);
        a[j] += __shfl_xor(a[j], 32);
    }
    if (grp == 0) {
        uint4 su = hs4[v * 16 + li];           // self-loop term (unscaled h)
        float dv = dinv[v];
        float4 b0 = *(const float4*)(bc + li * 8);
        float4 b1 = *(const float4*)(bc + li * 8 + 4);
        float f0 = dv * (a[0] + dv * bflo(su.x)) + b0.x;
        float f1 = dv * (a[1] + dv * bfhi(su.x)) + b0.y;
        float f2 = dv * (a[2] + dv * bflo(su.y)) + b0.z;
        float f3 = dv * (a[3] + dv * bfhi(su.y)) + b0.w;
        float f4 = dv * (a[4] + dv * bflo(su.z)) + b1.x;
        float f5 = dv * (a[5] + dv * bfhi(su.z)) + b1.y;
        float f6 = dv * (a[6] + dv * bflo(su.w)) + b1.z;
        float f7 = dv * (a[7] + dv * bfhi(su.w)) + b1.w;
        uint4 o;
        o.x = pk2(f0, f1); o.y = pk2(f2, f3); o.z = pk2(f4, f5); o.w = pk2(f6, f7);
        feat4[v * 16 + li] = o;
    }
}

// ---------------- logits[e] = dot(feat[src], feat[dst]) — 16 lanes/edge ----------------
__global__ void score_k(const int* __restrict__ src, const int* __restrict__ dst,
                        const uint4* __restrict__ feat4, float* __restrict__ out) {
    int gid = blockIdx.x * blockDim.x + threadIdx.x;
    int e = gid >> 4;
    int c = gid & 15;
    if (e >= N_PRED) return;
    int a = src[e], b = dst[e];
    uint4 ua = feat4[(long)a * 16 + c];
    uint4 ub = feat4[(long)b * 16 + c];
    float p = bflo(ua.x) * bflo(ub.x) + bfhi(ua.x) * bfhi(ub.x)
            + bflo(ua.y) * bflo(ub.y) + bfhi(ua.y) * bfhi(ub.y)
            + bflo(ua.z) * bflo(ub.z) + bfhi(ua.z) * bfhi(ub.z)
            + bflo(ua.w) * bflo(ub.w) + bfhi(ua.w) * bfhi(ub.w);
    #pragma unroll
    for (int m = 8; m; m >>= 1) p += __shfl_xor(p, m, 16);
    if (c == 0) out[e] = p;
}

extern "C" void kernel_launch(void* const* d_in, const int* in_sizes, int n_in,
                              void* d_out, int out_size, void* d_ws, size_t ws_size,
                              hipStream_t stream) {
    const float* x   = (const float*)d_in[0];
    const int*   ei  = (const int*)  d_in[1];   // [2, N_PRED]
    const int*   pe  = (const int*)  d_in[2];   // [2, N_POS]
    const float* W1  = (const float*)d_in[3];
    const float* b1  = (const float*)d_in[4];
    const float* Wc  = (const float*)d_in[5];
    const float* bc  = (const float*)d_in[6];
    float* out = (float*)d_out;

    const int* pe_row = pe;            // source
    const int* pe_col = pe + N_POS;    // target (aggregation)
    const int* ei_src = ei;
    const int* ei_dst = ei + N_PRED;

    // workspace layout (16B-aligned blocks)
    char* w = (char*)d_ws;
    unsigned short* Bp = (unsigned short*)w;  w += 32768 * 2;      // 64 KB
    float* bf    = (float*)w;                 w += 128 * 4;
    float* dinv  = (float*)w;                 w += 50000 * 4;
    int*   bfill = (int*)w;                   w += GPAD * 4;
    int*   offs  = (int*)w;                   w += 50000 * 4;
    int*   ends  = (int*)w;                   w += 50000 * 4;
    unsigned int* eb = (unsigned int*)w;      w += (long)G_BUCKETS * CAP * 4;    // 12.81 MB
    unsigned short* csr = (unsigned short*)w; w += (long)G_BUCKETS * CAP * 2;    // 6.4 MB
    unsigned short* hsb   = (unsigned short*)w;  w += (long)N_NODES * D_OUT * 2; // 12.8 MB
    unsigned short* featb = (unsigned short*)w;  // 12.8 MB

    // L1: weight fuse + cursor init (129 blocks: 0..127 weights, 128 cursors)
    fuse_weights_k<<<129, 256, 0, stream>>>(W1, Wc, b1, Bp, bf, bfill);

    // L2: fused gemm (782 blocks) || scatter (640 blocks) — independent roles
    scatter_gemm_k<<<GEMM_BLOCKS + SB, 256, 0, stream>>>(pe_row, pe_col, bfill, eb,
                                                         x, (const uint4*)Bp, bf, hsb);

    // L3: segmented CSR build (also emits offs/ends/dinv)
    csr_build_k   <<<G_BUCKETS, 256, 0, stream>>>(bfill, eb, csr, offs, ends, dinv);

    // L4: aggregation + finalize (dinv applied on the fly)
    aggregate_csr_k<<<N_NODES / 4, 256, 0, stream>>>(offs, ends, csr, (const uint4*)hsb,
                                                     dinv, bc, (uint4*)featb);

    // L5: scoring
    score_k       <<<(int)(((long)N_PRED * 16) / 256), 256, 0, stream>>>(
                      ei_src, ei_dst, (const uint4*)featb, out);
}